// Round 8
// baseline (267.280 us; speedup 1.0000x reference)
//
#include <hip/hip_runtime.h>

// Scatter2Operator: B=8, N=4096, G=64, D0=D2=1024, H=16, Dh=64
//   k  = softmax_g(x2 @ Wk^T)            [B*N, H*G=1024]
//   P  = x0 @ Wp^T                        [B*G=512, 1024]
//   Qt[b][d][h*64+g] = sum_dh P[b,g,h*64+dh] * Wo[d][h*64+dh]   [B,1024,1024]
//   out[b] = k[b] @ Qt[b]^T + bo          [B*N, 1024] f32

using bf16x8 = __attribute__((ext_vector_type(8))) __bf16;
using f32x4  = __attribute__((ext_vector_type(4))) float;

__device__ __forceinline__ unsigned short f2b(float f) {
  unsigned u = __float_as_uint(f);
  u += 0x7fffu + ((u >> 16) & 1u);   // RNE
  return (unsigned short)(u >> 16);
}

__global__ void cvt_f32_bf16(const float* __restrict__ in, unsigned short* __restrict__ out, int n4) {
  int i = blockIdx.x * blockDim.x + threadIdx.x;
  int stride = gridDim.x * blockDim.x;
  for (; i < n4; i += stride) {
    float4 v = reinterpret_cast<const float4*>(in)[i];
    ushort4 o;
    o.x = f2b(v.x); o.y = f2b(v.y); o.z = f2b(v.z); o.w = f2b(v.w);
    reinterpret_cast<ushort4*>(out)[i] = o;
  }
}

#define GLOAD_LDS(gsrc, ldst) __builtin_amdgcn_global_load_lds(                 \
    (const __attribute__((address_space(1))) unsigned int*)(gsrc),              \
    (__attribute__((address_space(3))) unsigned int*)(ldst), 16, 0, 0)

// Staging load opaque to the compiler's alias tracking (no conservative
// vmcnt(0) drains): raw M0 + global_load_lds_dwordx4. LDS dest = M0 + lane*16.
__device__ __forceinline__ void glds16(const unsigned short* g, unsigned ldsoff) {
  asm volatile("s_mov_b32 m0, %0\n\t"
               "global_load_lds_dwordx4 %1, off"
               :: "s"(ldsoff), "v"(g) : "memory");
}

// ---------------- small 128^2 kernel (for the two small GEMMs) ----------------
#define BM 128
#define BN 128
#define BK 32

template<int EPI>
__launch_bounds__(256)
__global__ void gemm_bt(const unsigned short* __restrict__ A,
                        const unsigned short* __restrict__ B,
                        void* __restrict__ Cv,
                        const float* __restrict__ bias,
                        int M, int N, int K, int lda, int ldb, int ldc,
                        int batch2,
                        long sA1, long sA2, long sB1, long sB2, long sC1, long sC2)
{
  __shared__ __align__(16) unsigned short As[BM * BK];
  __shared__ __align__(16) unsigned short Bs[BN * BK];

  const int z  = blockIdx.z;
  const int z1 = z / batch2, z2 = z - z1 * batch2;
  const unsigned short* Ab = A + z1 * sA1 + z2 * sA2;
  const unsigned short* Bb = B + z1 * sB1 + z2 * sB2;
  const long cbase = z1 * sC1 + z2 * sC2;

  const int tid  = threadIdx.x;
  const int lane = tid & 63;
  const int wid  = tid >> 6;
  const int wr   = (wid >> 1) * 64;
  const int wc   = (wid & 1) * 64;
  const int brow = blockIdx.x * BM;
  const int bcol = blockIdx.y * BN;
  const int lr   = lane & 15;
  const int ko   = (lane >> 4) * 8;

  f32x4 acc[4][4] = {};

  const int t1  = tid + 256;
  const int r0  = tid >> 2, kc0 = (tid & 3) * 8;
  const int r1  = t1 >> 2,  kc1 = (t1 & 3) * 8;
  int ar0 = brow + r0; if (ar0 >= M) ar0 = M - 1;
  int ar1 = brow + r1; if (ar1 >= M) ar1 = M - 1;
  int br0 = bcol + r0; if (br0 >= N) br0 = N - 1;
  int br1 = bcol + r1; if (br1 >= N) br1 = N - 1;
  const unsigned short* a0p = Ab + (long)ar0 * lda + kc0;
  const unsigned short* a1p = Ab + (long)ar1 * lda + kc1;
  const unsigned short* b0p = Bb + (long)br0 * ldb + kc0;
  const unsigned short* b1p = Bb + (long)br1 * ldb + kc1;

  for (int kt = 0; kt < K; kt += BK) {
    __syncthreads();
    GLOAD_LDS(a0p + kt, &As[tid * 8]);
    GLOAD_LDS(a1p + kt, &As[t1 * 8]);
    GLOAD_LDS(b0p + kt, &Bs[tid * 8]);
    GLOAD_LDS(b1p + kt, &Bs[t1 * 8]);
    __syncthreads();

    bf16x8 af[4], bfr[4];
#pragma unroll
    for (int m = 0; m < 4; ++m)
      af[m] = *reinterpret_cast<const bf16x8*>(&As[(wr + m * 16 + lr) * BK + ko]);
#pragma unroll
    for (int n = 0; n < 4; ++n)
      bfr[n] = *reinterpret_cast<const bf16x8*>(&Bs[(wc + n * 16 + lr) * BK + ko]);
#pragma unroll
    for (int m = 0; m < 4; ++m)
#pragma unroll
      for (int n = 0; n < 4; ++n)
        acc[m][n] = __builtin_amdgcn_mfma_f32_16x16x32_bf16(af[m], bfr[n], acc[m][n], 0, 0, 0);
  }

  const int rowb = brow + wr + (lane >> 4) * 4;
  const int colb = bcol + wc + lr;

  if (EPI == 1) {
    float* C = (float*)Cv + cbase;
#pragma unroll
    for (int n = 0; n < 4; ++n) {
      int col = colb + n * 16;
      if (col >= N) continue;
      float bv = bias ? bias[col] : 0.0f;
#pragma unroll
      for (int m = 0; m < 4; ++m)
#pragma unroll
        for (int r = 0; r < 4; ++r) {
          int row = rowb + m * 16 + r;
          if (row < M) C[(long)row * ldc + col] = acc[m][n][r] + bv;
        }
    }
  } else {
    unsigned short* C = (unsigned short*)Cv + cbase;
#pragma unroll
    for (int n = 0; n < 4; ++n) {
      int col = colb + n * 16;
      if (col >= N) continue;
#pragma unroll
      for (int m = 0; m < 4; ++m)
#pragma unroll
        for (int r = 0; r < 4; ++r) {
          int row = rowb + m * 16 + r;
          if (row < M) C[(long)row * ldc + col] = f2b(acc[m][n][r]);
        }
    }
  }
}

// ---------------- 256^2 8-phase kernel (big GEMMs) ----------------
// BM=BN=256, BK=64, 512 threads = 8 waves (2M x 4N), per-wave out 128x64.
// LDS 128KB: [A0 32K | B0 32K | A1 32K | B1 32K]; XOR swizzle byte^=(row&7)<<4.
// R8: template-faithful balanced phases — each phase reads exactly ONE
// C-quadrant's 12 frags (8 A + 4 B, halves re-read across phases) so the LDS
// port load is uniform (12 reads/phase) and hides under the previous phase's
// 16-MFMA cluster. Stage schedule: buf1's 4 half-tiles at ph1/ph2 (>=2-phase
// slack before ph5 consumption), buf0's at ph5/ph6; vmcnt(0) only at ph4/ph8
// (all outstanding loads nearly landed -> cheap drain).
// EPI: 1 = f32 + bias, 2 = bf16 with per-64col-group softmax.
// BATCHED: 0 -> grid(512): XCD-bijective swizzle over (bx 0..127, by 0..3).
//          1 -> grid(512): z=bid&7 (one batch per XCD), bx=(bid>>3)&15, by=bid>>7.

#define BARRIER() __builtin_amdgcn_s_barrier()
#define VMC0()   asm volatile("s_waitcnt vmcnt(0)" ::: "memory")

template<int EPI, int BATCHED>
__launch_bounds__(512)
__global__ void gemm256(const unsigned short* __restrict__ A,
                        const unsigned short* __restrict__ B,
                        void* __restrict__ Cv,
                        const float* __restrict__ bias,
                        int K, int lda, int ldb, int ldc,
                        long sA, long sB, long sC)
{
  extern __shared__ __align__(16) char smem[];

  const int tid  = threadIdx.x;
  const int lane = tid & 63, wid = tid >> 6;
  const int wm = wid >> 2, wn = wid & 3;
  const int lr = lane & 15, hi = lane >> 4;
  const int swz  = (lane & 7) << 4;            // ds_read byte-XOR
  const int prow = lane >> 3;                  // staging row within 8-row block
  const int pxor = ((lane & 7) ^ prow) * 8;    // pre-swizzled source col (elems)

  int bx, by; long abase = 0, bbase = 0, cbase = 0;
  if (BATCHED) {
    const int bid = blockIdx.x;
    const int z = bid & 7, idx = bid >> 3;
    bx = idx & 15; by = idx >> 4;
    abase = (long)z * sA; bbase = (long)z * sB; cbase = (long)z * sC;
  } else {
    const int bid = blockIdx.x;
    const int lin = (bid & 7) * 64 + (bid >> 3);
    bx = lin >> 2; by = lin & 3;
  }
  const int brow = bx * 256, bcol = by * 256;

  const unsigned short* __restrict__ Ab = A + abase;
  const unsigned short* __restrict__ Bb = B + bbase;

  unsigned short* ldsA[2] = { (unsigned short*)(smem),
                              (unsigned short*)(smem + 65536) };
  unsigned short* ldsB[2] = { (unsigned short*)(smem + 32768),
                              (unsigned short*)(smem + 98304) };

  const unsigned ldsbase =
      __builtin_amdgcn_readfirstlane((unsigned)(unsigned long long)smem);

  const long ldaL = lda, ldbL = ldb;

  auto stageA = [&](int buf, int h, int kt) {
    const unsigned short* s = Ab + (long)(brow + h * 128 + wid * 8 + prow) * ldaL + kt + pxor;
    unsigned d = ldsbase + (unsigned)(buf * 65536 + h * 16384 + wid * 1024);
    glds16(s, __builtin_amdgcn_readfirstlane(d));
    glds16(s + 64 * ldaL, __builtin_amdgcn_readfirstlane(d + 8192u));
  };
  auto stageB = [&](int buf, int h, int kt) {
    const unsigned short* s = Bb + (long)(bcol + h * 128 + wid * 8 + prow) * ldbL + kt + pxor;
    unsigned d = ldsbase + (unsigned)(32768 + buf * 65536 + h * 16384 + wid * 1024);
    glds16(s, __builtin_amdgcn_readfirstlane(d));
    glds16(s + 64 * ldbL, __builtin_amdgcn_readfirstlane(d + 8192u));
  };

  // Per-phase quadrant fragments (12 reads): A 4x2, B 2x2.
  bf16x8 aq[4][2], bq[2][2];
  auto ldAq = [&](int buf, int mh) {
    const unsigned short* base = ldsA[buf];
#pragma unroll
    for (int mi = 0; mi < 4; ++mi) {
      const int row = wm * 128 + mh * 64 + mi * 16 + lr;
#pragma unroll
      for (int ks = 0; ks < 2; ++ks) {
        const int cb = (ks * 64 + hi * 16) ^ swz;
        aq[mi][ks] = *(const bf16x8*)(base + row * 64 + (cb >> 1));
      }
    }
  };
  auto ldBq = [&](int buf, int nh) {
    const unsigned short* base = ldsB[buf];
#pragma unroll
    for (int ni = 0; ni < 2; ++ni) {
      const int row = wn * 64 + nh * 32 + ni * 16 + lr;
#pragma unroll
      for (int ks = 0; ks < 2; ++ks) {
        const int cb = (ks * 64 + hi * 16) ^ swz;
        bq[ni][ks] = *(const bf16x8*)(base + row * 64 + (cb >> 1));
      }
    }
  };

  f32x4 acc[8][4] = {};
  auto mma16 = [&](int mh, int nh) {
#pragma unroll
    for (int ks = 0; ks < 2; ++ks)
#pragma unroll
      for (int mi = 0; mi < 4; ++mi)
#pragma unroll
        for (int ni = 0; ni < 2; ++ni)
          acc[mh * 4 + mi][nh * 2 + ni] = __builtin_amdgcn_mfma_f32_16x16x32_bf16(
              aq[mi][ks], bq[ni][ks], acc[mh * 4 + mi][nh * 2 + ni], 0, 0, 0);
  };

  // Prologue: stage T0 fully into buf0.
  stageA(0, 0, 0); stageB(0, 0, 0); stageB(0, 1, 0); stageA(0, 1, 0);
  VMC0(); BARRIER();

  const int NI = K >> 7;   // 2 K-tiles (of 64) per iteration
#pragma unroll 1
  for (int i = 0; i < NI; ++i) {
    const int ktb1 = i * 128 + 64;                       // T(2i+1) -> buf1
    int ktb0 = i * 128 + 128; if (ktb0 >= K) ktb0 -= K;  // T(2i+2) -> buf0 (wrap: garbage, never read)

#define PHASE(BUF, MH, NH, STAGES, WAIT)                        \
    ldAq(BUF, MH); ldBq(BUF, NH);                               \
    STAGES;                                                     \
    BARRIER();                                                  \
    asm volatile("s_waitcnt lgkmcnt(0)" ::: "memory");          \
    __builtin_amdgcn_sched_barrier(0);                          \
    __builtin_amdgcn_s_setprio(1);                              \
    mma16(MH, NH);                                              \
    __builtin_amdgcn_s_setprio(0);                              \
    WAIT;                                                       \
    BARRIER();

    // ph1-4: consume buf0 (T2i); stage buf1 (T2i+1) early (ph1/ph2).
    PHASE(0, 0, 0, { stageA(1, 0, ktb1); stageB(1, 0, ktb1); }, )
    PHASE(0, 0, 1, { stageB(1, 1, ktb1); stageA(1, 1, ktb1); }, )
    PHASE(0, 1, 0, , )
    PHASE(0, 1, 1, , VMC0())
    // ph5-8: consume buf1 (T2i+1); stage buf0 (T2i+2) early (ph5/ph6).
    PHASE(1, 0, 0, { stageA(0, 0, ktb0); stageB(0, 0, ktb0); }, )
    PHASE(1, 0, 1, { stageB(0, 1, ktb0); stageA(0, 1, ktb0); }, )
    PHASE(1, 1, 0, , )
    PHASE(1, 1, 1, , VMC0())
#undef PHASE
  }
  VMC0();   // safety drain before LDS dealloc

  const int rowb = brow + wm * 128 + hi * 4;
  const int colb = bcol + wn * 64 + lr;

  if (EPI == 2) {
    unsigned short* C = (unsigned short*)Cv + cbase;
#pragma unroll
    for (int m = 0; m < 8; ++m) {
#pragma unroll
      for (int r = 0; r < 4; ++r) {
        float v0 = acc[m][0][r], v1 = acc[m][1][r], v2 = acc[m][2][r], v3 = acc[m][3][r];
        float mx = fmaxf(fmaxf(v0, v1), fmaxf(v2, v3));
        mx = fmaxf(mx, __shfl_xor(mx, 1));
        mx = fmaxf(mx, __shfl_xor(mx, 2));
        mx = fmaxf(mx, __shfl_xor(mx, 4));
        mx = fmaxf(mx, __shfl_xor(mx, 8));
        float e0 = __expf(v0 - mx), e1 = __expf(v1 - mx);
        float e2 = __expf(v2 - mx), e3 = __expf(v3 - mx);
        float s = e0 + e1 + e2 + e3;
        s += __shfl_xor(s, 1);
        s += __shfl_xor(s, 2);
        s += __shfl_xor(s, 4);
        s += __shfl_xor(s, 8);
        float inv = 1.0f / s;
        unsigned short* cp = C + (long)(rowb + m * 16 + r) * ldc + colb;
        cp[0]  = f2b(e0 * inv);
        cp[16] = f2b(e1 * inv);
        cp[32] = f2b(e2 * inv);
        cp[48] = f2b(e3 * inv);
      }
    }
  } else {
    float* C = (float*)Cv + cbase;
#pragma unroll
    for (int n = 0; n < 4; ++n) {
      const int col = colb + n * 16;
      const float bv = bias[col];
#pragma unroll
      for (int m = 0; m < 8; ++m)
#pragma unroll
        for (int r = 0; r < 4; ++r)
          C[(long)(rowb + m * 16 + r) * ldc + col] = acc[m][n][r] + bv;
    }
  }
}

extern "C" void kernel_launch(void* const* d_in, const int* in_sizes, int n_in,
                              void* d_out, int out_size, void* d_ws, size_t ws_size,
                              hipStream_t stream) {
  (void)in_sizes; (void)n_in; (void)out_size; (void)ws_size;
  const float* x0 = (const float*)d_in[0];
  const float* x2 = (const float*)d_in[1];
  const float* Wk = (const float*)d_in[2];
  const float* Wp = (const float*)d_in[3];
  const float* Wo = (const float*)d_in[4];
  const float* bo = (const float*)d_in[5];
  float* out = (float*)d_out;

  const long Bz = 8, Nn = 4096, Gg = 64, Dd = 1024;
  const long MN = Bz * Nn;  // 32768

  char* ws = (char*)d_ws;
  size_t off = 0;
  auto alloc = [&](size_t bytes) {
    size_t cur = off;
    off = (cur + bytes + 255) & ~(size_t)255;
    return (unsigned short*)(ws + cur);
  };
  unsigned short* x2b = alloc(MN * Dd * 2);       // 67 MB
  unsigned short* kb  = alloc(MN * Dd * 2);       // 67 MB
  unsigned short* Wkb = alloc(Dd * Dd * 2);
  unsigned short* Wpb = alloc(Dd * Dd * 2);
  unsigned short* Wob = alloc(Dd * Dd * 2);
  unsigned short* x0b = alloc(Bz * Gg * Dd * 2);
  unsigned short* Pb  = alloc(Bz * Gg * Dd * 2);
  unsigned short* Qtb = alloc(Bz * Dd * Dd * 2);  // 16.8 MB

  hipFuncSetAttribute(reinterpret_cast<const void*>(gemm256<2, 0>),
                      hipFuncAttributeMaxDynamicSharedMemorySize, 131072);
  hipFuncSetAttribute(reinterpret_cast<const void*>(gemm256<1, 1>),
                      hipFuncAttributeMaxDynamicSharedMemorySize, 131072);

  cvt_f32_bf16<<<dim3(4096), dim3(256), 0, stream>>>(x2, x2b, (int)(MN * Dd / 4));
  cvt_f32_bf16<<<dim3(512),  dim3(256), 0, stream>>>(x0, x0b, (int)(Bz * Gg * Dd / 4));
  cvt_f32_bf16<<<dim3(1024), dim3(256), 0, stream>>>(Wk, Wkb, (int)(Dd * Dd / 4));
  cvt_f32_bf16<<<dim3(1024), dim3(256), 0, stream>>>(Wp, Wpb, (int)(Dd * Dd / 4));
  cvt_f32_bf16<<<dim3(1024), dim3(256), 0, stream>>>(Wo, Wob, (int)(Dd * Dd / 4));

  // P = x0 @ Wp^T  [512 x 1024]
  gemm_bt<0><<<dim3(4, 8, 1), dim3(256), 0, stream>>>(
      x0b, Wpb, Pb, nullptr, 512, 1024, 1024, 1024, 1024, 1024,
      1, 0, 0, 0, 0, 0, 0);

  // kb = softmax_per_head(x2 @ Wk^T)  [32768 x 1024]
  gemm256<2, 0><<<dim3(512, 1, 1), dim3(512), 131072, stream>>>(
      x2b, Wkb, kb, nullptr, 1024, 1024, 1024, 1024, 0, 0, 0);

  // Qt[b][d][h*64+g] = sum_dh Wo[d][h*64+dh] * P[b*64+g][h*64+dh]
  gemm_bt<0><<<dim3(8, 1, 128), dim3(256), 0, stream>>>(
      Wob, Pb, Qtb, nullptr, 1024, 64, 64, 1024, 1024, 1024,
      16, 0, 64, 65536, 64, 1048576, 64);

  // out[b] = kb[b] @ Qt[b]^T + bo   [4096 x 1024] x 8, one batch per XCD
  gemm256<1, 1><<<dim3(512, 1, 1), dim3(512), 131072, stream>>>(
      kb, Qtb, (void*)out, bo, 1024, 1024, 1024, 1024,
      (long)4096 * 1024, (long)1024 * 1024, (long)4096 * 1024);
}

// Round 9
// 245.676 us; speedup vs baseline: 1.0879x; 1.0879x over previous
//
#include <hip/hip_runtime.h>

// Scatter2Operator: B=8, N=4096, G=64, D0=D2=1024, H=16, Dh=64
//   k  = softmax_g(x2 @ Wk^T)            [B*N, H*G=1024]
//   P  = x0 @ Wp^T                        [B*G=512, 1024]
//   Qt[b][d][h*64+g] = sum_dh P[b,g,h*64+dh] * Wo[d][h*64+dh]   [B,1024,1024]
//   out[b] = k[b] @ Qt[b]^T + bo          [B*N, 1024] f32

using bf16x8 = __attribute__((ext_vector_type(8))) __bf16;
using f32x4  = __attribute__((ext_vector_type(4))) float;

__device__ __forceinline__ unsigned short f2b(float f) {
  unsigned u = __float_as_uint(f);
  u += 0x7fffu + ((u >> 16) & 1u);   // RNE
  return (unsigned short)(u >> 16);
}

// One pass over all five f32 inputs -> bf16 (segmented grid-stride).
__global__ void cvt_all(const float* __restrict__ x2, unsigned short* __restrict__ x2b, int n0,
                        const float* __restrict__ x0, unsigned short* __restrict__ x0b, int n1,
                        const float* __restrict__ Wk, unsigned short* __restrict__ Wkb, int n2,
                        const float* __restrict__ Wp, unsigned short* __restrict__ Wpb, int n3,
                        const float* __restrict__ Wo, unsigned short* __restrict__ Wob, int n4)
{
  const int ntot = n0 + n1 + n2 + n3 + n4;
  int i = blockIdx.x * blockDim.x + threadIdx.x;
  const int stride = gridDim.x * blockDim.x;
  for (; i < ntot; i += stride) {
    const float* src; unsigned short* dst; int j = i;
    if (j < n0) { src = x2; dst = x2b; }
    else if ((j -= n0) < n1) { src = x0; dst = x0b; }
    else if ((j -= n1) < n2) { src = Wk; dst = Wkb; }
    else if ((j -= n2) < n3) { src = Wp; dst = Wpb; }
    else { j -= n3; src = Wo; dst = Wob; }
    float4 v = reinterpret_cast<const float4*>(src)[j];
    ushort4 o;
    o.x = f2b(v.x); o.y = f2b(v.y); o.z = f2b(v.z); o.w = f2b(v.w);
    reinterpret_cast<ushort4*>(dst)[j] = o;
  }
}

#define GLOAD_LDS(gsrc, ldst) __builtin_amdgcn_global_load_lds(                 \
    (const __attribute__((address_space(1))) unsigned int*)(gsrc),              \
    (__attribute__((address_space(3))) unsigned int*)(ldst), 16, 0, 0)

// Staging load opaque to the compiler's alias tracking (no conservative
// vmcnt(0) drains): raw M0 + global_load_lds_dwordx4. LDS dest = M0 + lane*16.
__device__ __forceinline__ void glds16(const unsigned short* g, unsigned ldsoff) {
  asm volatile("s_mov_b32 m0, %0\n\t"
               "global_load_lds_dwordx4 %1, off"
               :: "s"(ldsoff), "v"(g) : "memory");
}

// ---------------- small 128^2 kernel (for the two small GEMMs) ----------------
#define BM 128
#define BN 128
#define BK 32

template<int EPI>
__launch_bounds__(256)
__global__ void gemm_bt(const unsigned short* __restrict__ A,
                        const unsigned short* __restrict__ B,
                        void* __restrict__ Cv,
                        const float* __restrict__ bias,
                        int M, int N, int K, int lda, int ldb, int ldc,
                        int batch2,
                        long sA1, long sA2, long sB1, long sB2, long sC1, long sC2)
{
  __shared__ __align__(16) unsigned short As[BM * BK];
  __shared__ __align__(16) unsigned short Bs[BN * BK];

  const int z  = blockIdx.z;
  const int z1 = z / batch2, z2 = z - z1 * batch2;
  const unsigned short* Ab = A + z1 * sA1 + z2 * sA2;
  const unsigned short* Bb = B + z1 * sB1 + z2 * sB2;
  const long cbase = z1 * sC1 + z2 * sC2;

  const int tid  = threadIdx.x;
  const int lane = tid & 63;
  const int wid  = tid >> 6;
  const int wr   = (wid >> 1) * 64;
  const int wc   = (wid & 1) * 64;
  const int brow = blockIdx.x * BM;
  const int bcol = blockIdx.y * BN;
  const int lr   = lane & 15;
  const int ko   = (lane >> 4) * 8;

  f32x4 acc[4][4] = {};

  const int t1  = tid + 256;
  const int r0  = tid >> 2, kc0 = (tid & 3) * 8;
  const int r1  = t1 >> 2,  kc1 = (t1 & 3) * 8;
  int ar0 = brow + r0; if (ar0 >= M) ar0 = M - 1;
  int ar1 = brow + r1; if (ar1 >= M) ar1 = M - 1;
  int br0 = bcol + r0; if (br0 >= N) br0 = N - 1;
  int br1 = bcol + r1; if (br1 >= N) br1 = N - 1;
  const unsigned short* a0p = Ab + (long)ar0 * lda + kc0;
  const unsigned short* a1p = Ab + (long)ar1 * lda + kc1;
  const unsigned short* b0p = Bb + (long)br0 * ldb + kc0;
  const unsigned short* b1p = Bb + (long)br1 * ldb + kc1;

  for (int kt = 0; kt < K; kt += BK) {
    __syncthreads();
    GLOAD_LDS(a0p + kt, &As[tid * 8]);
    GLOAD_LDS(a1p + kt, &As[t1 * 8]);
    GLOAD_LDS(b0p + kt, &Bs[tid * 8]);
    GLOAD_LDS(b1p + kt, &Bs[t1 * 8]);
    __syncthreads();

    bf16x8 af[4], bfr[4];
#pragma unroll
    for (int m = 0; m < 4; ++m)
      af[m] = *reinterpret_cast<const bf16x8*>(&As[(wr + m * 16 + lr) * BK + ko]);
#pragma unroll
    for (int n = 0; n < 4; ++n)
      bfr[n] = *reinterpret_cast<const bf16x8*>(&Bs[(wc + n * 16 + lr) * BK + ko]);
#pragma unroll
    for (int m = 0; m < 4; ++m)
#pragma unroll
      for (int n = 0; n < 4; ++n)
        acc[m][n] = __builtin_amdgcn_mfma_f32_16x16x32_bf16(af[m], bfr[n], acc[m][n], 0, 0, 0);
  }

  const int rowb = brow + wr + (lane >> 4) * 4;
  const int colb = bcol + wc + lr;

  if (EPI == 1) {
    float* C = (float*)Cv + cbase;
#pragma unroll
    for (int n = 0; n < 4; ++n) {
      int col = colb + n * 16;
      if (col >= N) continue;
      float bv = bias ? bias[col] : 0.0f;
#pragma unroll
      for (int m = 0; m < 4; ++m)
#pragma unroll
        for (int r = 0; r < 4; ++r) {
          int row = rowb + m * 16 + r;
          if (row < M) C[(long)row * ldc + col] = acc[m][n][r] + bv;
        }
    }
  } else {
    unsigned short* C = (unsigned short*)Cv + cbase;
#pragma unroll
    for (int n = 0; n < 4; ++n) {
      int col = colb + n * 16;
      if (col >= N) continue;
#pragma unroll
      for (int m = 0; m < 4; ++m)
#pragma unroll
        for (int r = 0; r < 4; ++r) {
          int row = rowb + m * 16 + r;
          if (row < M) C[(long)row * ldc + col] = f2b(acc[m][n][r]);
        }
    }
  }
}

// ---------------- 256^2 8-phase kernel (big GEMMs) — R7 config (best) --------
// BM=BN=256, BK=64, 512 threads = 8 waves (2M x 4N), per-wave out 128x64.
// LDS 128KB: [A0 32K | B0 32K | A1 32K | B1 32K]; XOR swizzle byte^=(row&7)<<4.
// Staging via inline-asm global_load_lds (glds16): compiler cannot alias-track
// it, so no conservative vmcnt(0) drains before the C++ ds_reads; the ONLY
// vmem waits are the counted vmcnt(4) at ph4/ph8. mmaQ is ks-outer (8
// independent MFMAs between dependent accumulator reuses). No lgkm pinning —
// compiler emits counted lgkmcnt interleaving ds_read arrival with MFMA issue.
// EPI: 1 = f32 + bias, 2 = bf16 with per-64col-group softmax.
// BATCHED: 0 -> grid(512): XCD-bijective swizzle over (bx 0..127, by 0..3).
//          1 -> grid(512): z=bid&7 (one batch per XCD), bx=(bid>>3)&15, by=bid>>7.

#define BARRIER() __builtin_amdgcn_s_barrier()
#define VMC4()   asm volatile("s_waitcnt vmcnt(4)" ::: "memory")
#define VMC0()   asm volatile("s_waitcnt vmcnt(0)" ::: "memory")

template<int EPI, int BATCHED>
__launch_bounds__(512)
__global__ void gemm256(const unsigned short* __restrict__ A,
                        const unsigned short* __restrict__ B,
                        void* __restrict__ Cv,
                        const float* __restrict__ bias,
                        int K, int lda, int ldb, int ldc,
                        long sA, long sB, long sC)
{
  extern __shared__ __align__(16) char smem[];

  const int tid  = threadIdx.x;
  const int lane = tid & 63, wid = tid >> 6;
  const int wm = wid >> 2, wn = wid & 3;
  const int lr = lane & 15, hi = lane >> 4;
  const int swz  = (lane & 7) << 4;            // ds_read byte-XOR
  const int prow = lane >> 3;                  // staging row within 8-row block
  const int pxor = ((lane & 7) ^ prow) * 8;    // pre-swizzled source col (elems)

  int bx, by; long abase = 0, bbase = 0, cbase = 0;
  if (BATCHED) {
    const int bid = blockIdx.x;
    const int z = bid & 7, idx = bid >> 3;
    bx = idx & 15; by = idx >> 4;
    abase = (long)z * sA; bbase = (long)z * sB; cbase = (long)z * sC;
  } else {
    const int bid = blockIdx.x;
    const int lin = (bid & 7) * 64 + (bid >> 3);
    bx = lin >> 2; by = lin & 3;
  }
  const int brow = bx * 256, bcol = by * 256;

  const unsigned short* __restrict__ Ab = A + abase;
  const unsigned short* __restrict__ Bb = B + bbase;

  unsigned short* ldsA[2] = { (unsigned short*)(smem),
                              (unsigned short*)(smem + 65536) };
  unsigned short* ldsB[2] = { (unsigned short*)(smem + 32768),
                              (unsigned short*)(smem + 98304) };

  const unsigned ldsbase =
      __builtin_amdgcn_readfirstlane((unsigned)(unsigned long long)smem);

  const long ldaL = lda, ldbL = ldb;

  auto stageA = [&](int buf, int h, int kt) {
    const unsigned short* s = Ab + (long)(brow + h * 128 + wid * 8 + prow) * ldaL + kt + pxor;
    unsigned d = ldsbase + (unsigned)(buf * 65536 + h * 16384 + wid * 1024);
    glds16(s, __builtin_amdgcn_readfirstlane(d));
    glds16(s + 64 * ldaL, __builtin_amdgcn_readfirstlane(d + 8192u));
  };
  auto stageB = [&](int buf, int h, int kt) {
    const unsigned short* s = Bb + (long)(bcol + h * 128 + wid * 8 + prow) * ldbL + kt + pxor;
    unsigned d = ldsbase + (unsigned)(32768 + buf * 65536 + h * 16384 + wid * 1024);
    glds16(s, __builtin_amdgcn_readfirstlane(d));
    glds16(s + 64 * ldbL, __builtin_amdgcn_readfirstlane(d + 8192u));
  };

  bf16x8 afr[4][2], bfr[4][2];
  auto ldA_ = [&](int buf, int mh) {
    const unsigned short* base = ldsA[buf];
#pragma unroll
    for (int mi = 0; mi < 4; ++mi) {
      const int row = wm * 128 + mh * 64 + mi * 16 + lr;
#pragma unroll
      for (int ks = 0; ks < 2; ++ks) {
        const int cb = (ks * 64 + hi * 16) ^ swz;
        afr[mi][ks] = *(const bf16x8*)(base + row * 64 + (cb >> 1));
      }
    }
  };
  auto ldB_ = [&](int buf, int nh) {
    const unsigned short* base = ldsB[buf];
#pragma unroll
    for (int ni = 0; ni < 2; ++ni) {
      const int row = wn * 64 + nh * 32 + ni * 16 + lr;
#pragma unroll
      for (int ks = 0; ks < 2; ++ks) {
        const int cb = (ks * 64 + hi * 16) ^ swz;
        bfr[nh * 2 + ni][ks] = *(const bf16x8*)(base + row * 64 + (cb >> 1));
      }
    }
  };

  f32x4 acc[8][4] = {};
  auto mmaQ = [&](int mh, int nh) {
    __builtin_amdgcn_s_setprio(1);
#pragma unroll
    for (int ks = 0; ks < 2; ++ks)
#pragma unroll
      for (int mi = 0; mi < 4; ++mi)
#pragma unroll
        for (int ni = 0; ni < 2; ++ni)
          acc[mh * 4 + mi][nh * 2 + ni] = __builtin_amdgcn_mfma_f32_16x16x32_bf16(
              afr[mi][ks], bfr[nh * 2 + ni][ks], acc[mh * 4 + mi][nh * 2 + ni], 0, 0, 0);
    __builtin_amdgcn_s_setprio(0);
  };

  // Prologue: stage T0 (B,A) into buf0, B of T1 into buf1. vmcnt(4) => T0 landed.
  stageB(0, 0, 0); stageB(0, 1, 0); stageA(0, 0, 0); stageA(0, 1, 0);
  stageB(1, 0, 64); stageB(1, 1, 64);
  VMC4(); BARRIER();

  const int NI = K >> 7;   // 2 K-tiles (of 64) per iteration
#pragma unroll 1
  for (int i = 0; i < NI; ++i) {
    const int kt1 = i * 128 + 64;
    int kt2 = i * 128 + 128; if (kt2 >= K) kt2 -= K;   // wrapped: harmless garbage
    int kt3 = i * 128 + 192; if (kt3 >= K) kt3 -= K;

    // ph1: Q(mLo,nLo) of T0; prefetch ALL B-frags of T0; stage A-half0(T1)
    ldA_(0, 0); ldB_(0, 0); ldB_(0, 1); stageA(1, 0, kt1);
    BARRIER(); mmaQ(0, 0); BARRIER();
    // ph2: Q(mLo,nHi); stage A-half1(T1)
    stageA(1, 1, kt1);
    BARRIER(); mmaQ(0, 1); BARRIER();
    // ph3: Q(mHi,nLo); stage B-half0(T2) (buf0 B free after ph2)
    ldA_(0, 1); stageB(0, 0, kt2);
    BARRIER(); mmaQ(1, 0); BARRIER();
    // ph4: Q(mHi,nHi); stage B-half1(T2); vmcnt(4) => T1 landed
    stageB(0, 1, kt2); VMC4();
    BARRIER(); mmaQ(1, 1); BARRIER();
    // ph5: T1 from buf1; stage A-half0(T2) (buf0 A free after ph3)
    ldA_(1, 0); ldB_(1, 0); ldB_(1, 1); stageA(0, 0, kt2);
    BARRIER(); mmaQ(0, 0); BARRIER();
    // ph6
    stageA(0, 1, kt2);
    BARRIER(); mmaQ(0, 1); BARRIER();
    // ph7: stage B-half0(T3) (buf1 B free after ph6)
    ldA_(1, 1); stageB(1, 0, kt3);
    BARRIER(); mmaQ(1, 0); BARRIER();
    // ph8: stage B-half1(T3); vmcnt(4) => T2 landed
    stageB(1, 1, kt3); VMC4();
    BARRIER(); mmaQ(1, 1); BARRIER();
  }
  VMC0();   // drain wrapped garbage loads before LDS dealloc

  const int rowb = brow + wm * 128 + hi * 4;
  const int colb = bcol + wn * 64 + lr;

  if (EPI == 2) {
    unsigned short* C = (unsigned short*)Cv + cbase;
#pragma unroll
    for (int m = 0; m < 8; ++m) {
#pragma unroll
      for (int r = 0; r < 4; ++r) {
        float v0 = acc[m][0][r], v1 = acc[m][1][r], v2 = acc[m][2][r], v3 = acc[m][3][r];
        float mx = fmaxf(fmaxf(v0, v1), fmaxf(v2, v3));
        mx = fmaxf(mx, __shfl_xor(mx, 1));
        mx = fmaxf(mx, __shfl_xor(mx, 2));
        mx = fmaxf(mx, __shfl_xor(mx, 4));
        mx = fmaxf(mx, __shfl_xor(mx, 8));
        float e0 = __expf(v0 - mx), e1 = __expf(v1 - mx);
        float e2 = __expf(v2 - mx), e3 = __expf(v3 - mx);
        float s = e0 + e1 + e2 + e3;
        s += __shfl_xor(s, 1);
        s += __shfl_xor(s, 2);
        s += __shfl_xor(s, 4);
        s += __shfl_xor(s, 8);
        float inv = 1.0f / s;
        unsigned short* cp = C + (long)(rowb + m * 16 + r) * ldc + colb;
        cp[0]  = f2b(e0 * inv);
        cp[16] = f2b(e1 * inv);
        cp[32] = f2b(e2 * inv);
        cp[48] = f2b(e3 * inv);
      }
    }
  } else {
    float* C = (float*)Cv + cbase;
#pragma unroll
    for (int n = 0; n < 4; ++n) {
      const int col = colb + n * 16;
      const float bv = bias[col];
#pragma unroll
      for (int m = 0; m < 8; ++m)
#pragma unroll
        for (int r = 0; r < 4; ++r)
          C[(long)(rowb + m * 16 + r) * ldc + col] = acc[m][n][r] + bv;
    }
  }
}

extern "C" void kernel_launch(void* const* d_in, const int* in_sizes, int n_in,
                              void* d_out, int out_size, void* d_ws, size_t ws_size,
                              hipStream_t stream) {
  (void)in_sizes; (void)n_in; (void)out_size; (void)ws_size;
  const float* x0 = (const float*)d_in[0];
  const float* x2 = (const float*)d_in[1];
  const float* Wk = (const float*)d_in[2];
  const float* Wp = (const float*)d_in[3];
  const float* Wo = (const float*)d_in[4];
  const float* bo = (const float*)d_in[5];
  float* out = (float*)d_out;

  const long Bz = 8, Nn = 4096, Gg = 64, Dd = 1024;
  const long MN = Bz * Nn;  // 32768

  char* ws = (char*)d_ws;
  size_t off = 0;
  auto alloc = [&](size_t bytes) {
    size_t cur = off;
    off = (cur + bytes + 255) & ~(size_t)255;
    return (unsigned short*)(ws + cur);
  };
  unsigned short* x2b = alloc(MN * Dd * 2);       // 67 MB
  unsigned short* kb  = alloc(MN * Dd * 2);       // 67 MB
  unsigned short* Wkb = alloc(Dd * Dd * 2);
  unsigned short* Wpb = alloc(Dd * Dd * 2);
  unsigned short* Wob = alloc(Dd * Dd * 2);
  unsigned short* x0b = alloc(Bz * Gg * Dd * 2);
  unsigned short* Pb  = alloc(Bz * Gg * Dd * 2);
  unsigned short* Qtb = alloc(Bz * Dd * Dd * 2);  // 16.8 MB

  hipFuncSetAttribute(reinterpret_cast<const void*>(gemm256<2, 0>),
                      hipFuncAttributeMaxDynamicSharedMemorySize, 131072);
  hipFuncSetAttribute(reinterpret_cast<const void*>(gemm256<1, 1>),
                      hipFuncAttributeMaxDynamicSharedMemorySize, 131072);

  // Single cvt pass over all five f32 inputs.
  cvt_all<<<dim3(4096), dim3(256), 0, stream>>>(
      x2, x2b, (int)(MN * Dd / 4),
      x0, x0b, (int)(Bz * Gg * Dd / 4),
      Wk, Wkb, (int)(Dd * Dd / 4),
      Wp, Wpb, (int)(Dd * Dd / 4),
      Wo, Wob, (int)(Dd * Dd / 4));

  // P = x0 @ Wp^T  [512 x 1024]
  gemm_bt<0><<<dim3(4, 8, 1), dim3(256), 0, stream>>>(
      x0b, Wpb, Pb, nullptr, 512, 1024, 1024, 1024, 1024, 1024,
      1, 0, 0, 0, 0, 0, 0);

  // kb = softmax_per_head(x2 @ Wk^T)  [32768 x 1024]
  gemm256<2, 0><<<dim3(512, 1, 1), dim3(512), 131072, stream>>>(
      x2b, Wkb, kb, nullptr, 1024, 1024, 1024, 1024, 0, 0, 0);

  // Qt[b][d][h*64+g] = sum_dh Wo[d][h*64+dh] * P[b*64+g][h*64+dh]
  gemm_bt<0><<<dim3(8, 1, 128), dim3(256), 0, stream>>>(
      Wob, Pb, Qtb, nullptr, 1024, 64, 64, 1024, 1024, 1024,
      16, 0, 64, 65536, 64, 1048576, 64);

  // out[b] = kb[b] @ Qt[b]^T + bo   [4096 x 1024] x 8, one batch per XCD
  gemm256<1, 1><<<dim3(512, 1, 1), dim3(512), 131072, stream>>>(
      kb, Qtb, (void*)out, bo, 1024, 1024, 1024, 1024,
      (long)4096 * 1024, (long)1024 * 1024, (long)4096 * 1024);
}